// Round 18
// baseline (938.056 us; speedup 1.0000x reference)
//
#include <hip/hip_runtime.h>
#include <math.h>

#define BB 4
#define NN 6
#define DD 41
#define CC 64
#define FHh 16
#define FWw 44
#define NXg 200
#define NYg 200
#define NZg 1
#define NSLOT 128
#define NOVF  (FHh*DD)                 // 656 worst-case points per column
#define XYg (NXg*NYg)                  // 40000
#define NVOX (BB*NZg*NXg*NYg)          // 160000
#define NCOL (BB*NN*FWw)               // 1056 columns
#define NPIX (BB*NN*FHh*FWw)           // 16896
#define NCH  (DD+CC)                   // 105
#define NTILE (NVOX/64)                // 2500

// ws layout: wsv[NVOX][CC] | claim[NVOX] ints | bmapT[2500->2560]
#define WSV_BYTES  40960000u
#define CLAIM_OFF  40960000u           // NVOX*4 = 640000
#define BMAPT_OFF  41600000u           // 2560
#define CTL_BYTES  642560u             // claim + bmapT (one memset)
#define WS_NEED    41602560u

__device__ __forceinline__ void inv3x3d(const double m[9], double o[9]) {
    double a=m[0],b=m[1],c=m[2],d=m[3],e=m[4],f=m[5],g=m[6],h=m[7],i=m[8];
    double A = e*i - f*h;
    double Bv = -(d*i - f*g);
    double Cv = d*h - e*g;
    double det = a*A + b*Bv + c*Cv;
    double r = 1.0/det;
    o[0]=A*r;  o[1]=-(b*i-c*h)*r; o[2]=(b*f-c*e)*r;
    o[3]=Bv*r; o[4]=(a*i-c*g)*r;  o[5]=-(a*f-c*d)*r;
    o[6]=Cv*r; o[7]=-(a*h-b*g)*r; o[8]=(a*e-b*d)*r;
}

__global__ __launch_bounds__(256)
void lss_zero(float4* __restrict__ p, int n4)
{
    const int stride = gridDim.x * 256;
    for (int i = blockIdx.x * 256 + threadIdx.x; i < n4; i += stride)
        p[i] = make_float4(0.f, 0.f, 0.f, 0.f);
}

// One block (256 thr, 4 waves) per (b,n,w) column. R15 front (logit prefetch,
// feat stage, f64 geometry, LDS hash dedup), then claim-based emit:
// first writer to a voxel row plain-stores the full 64-float row (no pre-zero
// needed), fences, releases claim=2; later writers wait for release (distinct
// lines, backoff) then atomicAdd. No global barrier anywhere.
__global__ __launch_bounds__(256)
void lss_scatter_claim(const float* __restrict__ xf,
                       const float* __restrict__ rots,
                       const float* __restrict__ trans,
                       const float* __restrict__ intr,
                       const float* __restrict__ prots,
                       const float* __restrict__ ptrans,
                       float* __restrict__ ws,
                       int* __restrict__ claim,
                       unsigned char* __restrict__ bmapT)
{
    __shared__ float s_feat[FHh * CC];
    __shared__ float s_coef[NSLOT * 17];
    __shared__ int   s_keys[NSLOT];
    __shared__ short s_list[NSLOT];
    __shared__ int   s_nslot;
    __shared__ int2  s_ovf[NOVF];
    __shared__ float s_ovfw[NOVF];
    __shared__ int   s_ovfcnt;

    const int tid  = threadIdx.x;
    const int lane = tid & 63;
    const int wv   = tid >> 6;          // 0..3

    // XCD swizzle: 1056 = 8*132
    const int obid = blockIdx.x;
    const int bid  = (obid & 7) * (NCOL / 8) + (obid >> 3);
    const int w   = bid % FWw;
    const int rem = bid / FWw;
    const int n   = rem % NN;
    const int b   = rem / NN;
    const int cam = b*NN + n;
    const float* colbase = xf + (size_t)cam * NCH * FHh * FWw + w;

    // ---- prefetch this lane's 4 logits ----
    float lgt[4];
    #pragma unroll
    for (int r = 0; r < 4; ++r) {
        const int h = (wv << 2) + r;
        lgt[r] = (lane < DD)
            ? colbase[(size_t)lane * (FHh*FWw) + h * FWw] : -INFINITY;
    }

    if (tid < NSLOT) s_keys[tid] = -1;
    for (int i = tid; i < NSLOT*17; i += 256) s_coef[i] = 0.0f;
    if (tid == 0) { s_nslot = 0; s_ovfcnt = 0; }

    // ---- stage the reused features: 1024 scalars ----
    for (int t = tid; t < FHh*CC; t += 256) {
        int h = t >> 6, c = t & 63;
        s_feat[t] = colbase[(size_t)(DD + c) * (FHh*FWw) + h * FWw];
    }

    // ---- per-camera transform (f64, redundant per thread) ----
    double K9[9], P9[9], R9[9];
    #pragma unroll
    for (int i = 0; i < 9; ++i) {
        K9[i] = (double)intr [cam*9 + i];
        P9[i] = (double)prots[cam*9 + i];
        R9[i] = (double)rots [cam*9 + i];
    }
    double Kinv[9], Pinv[9];
    inv3x3d(K9, Kinv);
    inv3x3d(P9, Pinv);
    double M[9];
    #pragma unroll
    for (int i = 0; i < 3; ++i)
        #pragma unroll
        for (int j = 0; j < 3; ++j)
            M[i*3+j] = R9[i*3+0]*Kinv[0*3+j] + R9[i*3+1]*Kinv[1*3+j] + R9[i*3+2]*Kinv[2*3+j];
    const double tx  = (double)trans [cam*3+0], ty  = (double)trans [cam*3+1], tz  = (double)trans [cam*3+2];
    const double ptx = (double)ptrans[cam*3+0], pty = (double)ptrans[cam*3+1], ptz = (double)ptrans[cam*3+2];

    __syncthreads();

    // ---- softmax + geometry + hash insert; wave wv handles h = 4wv..4wv+3
    int      last_vox  = -1;
    unsigned last_slot = 0;
    for (int r = 0; r < 4; ++r) {
        const int h = (wv << 2) + r;
        float logit = lgt[r];
        float mx = logit;
        #pragma unroll
        for (int off = 32; off; off >>= 1) mx = fmaxf(mx, __shfl_xor(mx, off));
        float ex = (lane < DD) ? expf(logit - mx) : 0.0f;
        float sm = ex;
        #pragma unroll
        for (int off = 32; off; off >>= 1) sm += __shfl_xor(sm, off);
        const float wgt = ex / sm;

        int vox = -1;
        if (lane < DD) {
            double dz = 4.0 + (double)lane;
            double xs = (double)w * (703.0/43.0);
            double ys = (double)h * 17.0;
            double px = xs - ptx, py = ys - pty, pz = dz - ptz;
            double qx = Pinv[0]*px + Pinv[1]*py + Pinv[2]*pz;
            double qy = Pinv[3]*px + Pinv[4]*py + Pinv[5]*pz;
            double qz = Pinv[6]*px + Pinv[7]*py + Pinv[8]*pz;
            qx *= qz; qy *= qz;
            double gx = M[0]*qx + M[1]*qy + M[2]*qz + tx;
            double gy = M[3]*qx + M[4]*qy + M[5]*qz + ty;
            double gz = M[6]*qx + M[7]*qy + M[8]*qz + tz;
            double fx = floor((gx + 50.0) / 0.5);
            double fy = floor((gy + 50.0) / 0.5);
            double fz = floor((gz + 10.0) / 20.0);
            if (fx >= 0.0 && fx < (double)NXg &&
                fy >= 0.0 && fy < (double)NYg &&
                fz >= 0.0 && fz < (double)NZg) {
                int ix = (int)fx, iy = (int)fy, iz = (int)fz;
                vox = ((b*NZg + iz)*NXg + ix)*NYg + iy;   // < 160000
            }
        }

        if (vox >= 0) {
            if (vox == last_vox) {
                atomicAdd(&s_coef[last_slot*17 + h], wgt);
            } else {
                unsigned slot = (((unsigned)vox * 2654435761u) >> 18) & (NSLOT-1);
                bool done = false;
                for (int probe = 0; probe < NSLOT; ++probe) {
                    int prev = atomicCAS(&s_keys[slot], -1, vox);
                    if (prev == -1) {
                        int k = atomicAdd(&s_nslot, 1);
                        s_list[k] = (short)slot;
                    }
                    if (prev == -1 || prev == vox) {
                        atomicAdd(&s_coef[slot*17 + h], wgt);
                        last_vox = vox; last_slot = slot;
                        done = true;
                        break;
                    }
                    slot = (slot + 1) & (NSLOT-1);
                }
                if (!done) {
                    int k = atomicAdd(&s_ovfcnt, 1);
                    s_ovf[k]  = make_int2(vox, h);
                    s_ovfw[k] = wgt;
                    last_vox = -1;
                }
            }
        }
    }

    __syncthreads();

    // ---- hoist this lane's 16 feature values into registers ----
    float freg[FHh];
    #pragma unroll
    for (int h = 0; h < FHh; ++h) freg[h] = s_feat[(h << 6) + lane];

    // ---- claim-based emit: one row per unique voxel ----
    const int nocc = s_nslot;
    for (int e = wv; e < nocc; e += 4) {
        int slot = s_list[e];
        int vox  = s_keys[slot];
        float acc = 0.0f;
        #pragma unroll
        for (int h = 0; h < FHh; ++h)
            acc += s_coef[slot*17 + h] * freg[h];

        int old = 0;
        if (lane == 0) old = atomicCAS(&claim[vox], 0, 1);
        old = __shfl(old, 0);
        float* row = &ws[(size_t)vox * CC + lane];
        if (old == 0) {
            *row = acc;                       // full 256B row covered by wave
            __threadfence();                  // row visible before release
            if (lane == 0) {
                atomicExch(&claim[vox], 2);   // release
                bmapT[vox >> 6] = 1;
            }
        } else {
            if (lane == 0) {
                while (__hip_atomic_load(&claim[vox], __ATOMIC_RELAXED,
                                         __HIP_MEMORY_SCOPE_AGENT) != 2)
                    __builtin_amdgcn_s_sleep(32);
            }
            old = __shfl(old, 0);             // reconverge wave after spin
            __threadfence();                  // acquire: row store visible
            atomicAdd(row, acc);
        }
    }
    // ---- overflow entries (rare, generic fallback): same protocol ----
    const int novf = s_ovfcnt;
    for (int e = wv; e < novf; e += 4) {
        int vox = s_ovf[e].x, h = s_ovf[e].y;
        float acc = s_ovfw[e] * freg[h];
        int old = 0;
        if (lane == 0) old = atomicCAS(&claim[vox], 0, 1);
        old = __shfl(old, 0);
        float* row = &ws[(size_t)vox * CC + lane];
        if (old == 0) {
            *row = acc;
            __threadfence();
            if (lane == 0) {
                atomicExch(&claim[vox], 2);
                bmapT[vox >> 6] = 1;
            }
        } else {
            if (lane == 0) {
                while (__hip_atomic_load(&claim[vox], __ATOMIC_RELAXED,
                                         __HIP_MEMORY_SCOPE_AGENT) != 2)
                    __builtin_amdgcn_s_sleep(32);
            }
            old = __shfl(old, 0);
            __threadfence();
            atomicAdd(row, acc);
        }
    }
}

// ws [bz][40000 xy][64 c] -> out [bz][64 c][40000 xy]
// tile gate: bmapT byte; cell gate: claim[vox] != 0 (unclaimed rows = poison).
__global__ __launch_bounds__(256)
void lss_transpose_c2(const float* __restrict__ ws,
                      const int* __restrict__ claim,
                      const unsigned char* __restrict__ bmapT,
                      float* __restrict__ out)
{
    __shared__ float tile[CC][65];
    const int blk  = blockIdx.x;            // 2500 blocks; tile id == blk
    const int bz   = blk / 625;
    const int xy0  = (blk % 625) * 64;
    const int t    = threadIdx.x;
    const int lane = t & 63;
    const int wv   = t >> 6;

    float* dst = out + (size_t)bz * CC * XYg + xy0;
    if (bmapT[blk] == 0) {
        const float4 z = make_float4(0.f, 0.f, 0.f, 0.f);
        #pragma unroll
        for (int rep = 0; rep < 4; ++rep) {
            int c = (wv << 4) + (rep << 2) + (lane >> 4);
            int q = lane & 15;
            ((float4*)(dst + (size_t)c * XYg))[q] = z;
        }
        return;
    }

    const int vb = bz * XYg + xy0;
    const float4* src = (const float4*)(ws + (size_t)vb * CC);
    const float4 z4 = make_float4(0.f, 0.f, 0.f, 0.f);
    #pragma unroll
    for (int rep = 0; rep < 4; ++rep) {
        int idx = (wv << 8) + (rep << 6) + lane;
        int xyl = idx >> 4;
        int c4  = idx & 15;
        float4 v = (claim[vb + xyl] != 0) ? src[idx] : z4;
        tile[(c4<<2)+0][xyl] = v.x;
        tile[(c4<<2)+1][xyl] = v.y;
        tile[(c4<<2)+2][xyl] = v.z;
        tile[(c4<<2)+3][xyl] = v.w;
    }
    __syncthreads();
    #pragma unroll
    for (int rep = 0; rep < 4; ++rep) {
        int c   = (wv << 4) + (rep << 2) + (lane >> 4);
        int xy4 = lane & 15;
        float4 v = make_float4(tile[c][(xy4<<2)+0], tile[c][(xy4<<2)+1],
                               tile[c][(xy4<<2)+2], tile[c][(xy4<<2)+3]);
        ((float4*)(dst + (size_t)c * XYg))[xy4] = v;
    }
}

// ---------------- fallback (tiny ws): zero out + direct atomics -------------
__global__ __launch_bounds__(256)
void lss_scatter_direct(const float* __restrict__ xf,
                        const float* __restrict__ rots,
                        const float* __restrict__ trans,
                        const float* __restrict__ intr,
                        const float* __restrict__ prots,
                        const float* __restrict__ ptrans,
                        float* __restrict__ acc)
{
    const int wid  = blockIdx.x * 4 + (threadIdx.x >> 6);
    const int lane = threadIdx.x & 63;
    if (wid >= NPIX) return;
    int w  = wid % FWw;
    int t1 = wid / FWw;
    int h  = t1 % FHh; t1 /= FHh;
    int n  = t1 % NN;
    int b  = t1 / NN;
    const int cam = b*NN + n;

    double K9[9], P9[9], R9[9];
    #pragma unroll
    for (int i = 0; i < 9; ++i) {
        K9[i] = (double)intr [cam*9 + i];
        P9[i] = (double)prots[cam*9 + i];
        R9[i] = (double)rots [cam*9 + i];
    }
    double Kinv[9], Pinv[9];
    inv3x3d(K9, Kinv);
    inv3x3d(P9, Pinv);
    double M[9];
    #pragma unroll
    for (int i = 0; i < 3; ++i)
        #pragma unroll
        for (int j = 0; j < 3; ++j)
            M[i*3+j] = R9[i*3+0]*Kinv[0*3+j] + R9[i*3+1]*Kinv[1*3+j] + R9[i*3+2]*Kinv[2*3+j];
    const double tx  = (double)trans [cam*3+0], ty  = (double)trans [cam*3+1], tz  = (double)trans [cam*3+2];
    const double ptx = (double)ptrans[cam*3+0], pty = (double)ptrans[cam*3+1], ptz = (double)ptrans[cam*3+2];

    const size_t pixoff = (size_t)cam * NCH * FHh * FWw + (size_t)h * FWw + w;
    float logit = (lane < DD) ? xf[pixoff + (size_t)lane * (FHh*FWw)] : -INFINITY;
    float mx = logit;
    #pragma unroll
    for (int off = 32; off; off >>= 1) mx = fmaxf(mx, __shfl_xor(mx, off));
    float ex = (lane < DD) ? expf(logit - mx) : 0.0f;
    float sm = ex;
    #pragma unroll
    for (int off = 32; off; off >>= 1) sm += __shfl_xor(sm, off);
    const float wgt = ex / sm;

    int baddr = -1;
    if (lane < DD) {
        double dz = 4.0 + (double)lane;
        double xs = (double)w * (703.0/43.0);
        double ys = (double)h * 17.0;
        double px = xs - ptx, py = ys - pty, pz = dz - ptz;
        double qx = Pinv[0]*px + Pinv[1]*py + Pinv[2]*pz;
        double qy = Pinv[3]*px + Pinv[4]*py + Pinv[5]*pz;
        double qz = Pinv[6]*px + Pinv[7]*py + Pinv[8]*pz;
        qx *= qz; qy *= qz;
        double gx = M[0]*qx + M[1]*qy + M[2]*qz + tx;
        double gy = M[3]*qx + M[4]*qy + M[5]*qz + ty;
        double gz = M[6]*qx + M[7]*qy + M[8]*qz + tz;
        double fx = floor((gx + 50.0) / 0.5);
        double fy = floor((gy + 50.0) / 0.5);
        double fz = floor((gz + 10.0) / 20.0);
        if (fx >= 0.0 && fx < (double)NXg &&
            fy >= 0.0 && fy < (double)NYg &&
            fz >= 0.0 && fz < (double)NZg) {
            int ix = (int)fx, iy = (int)fy, iz = (int)fz;
            int bz = b*NZg + iz;
            baddr = bz * (CC*XYg) + ix*NYg + iy;
        }
    }

    const float f = xf[pixoff + (size_t)(DD + lane) * (FHh*FWw)];
    for (int d = 0; d < DD; ++d) {
        int   a  = __shfl(baddr, d);
        float wd = __shfl(wgt,   d);
        if (a >= 0) atomicAdd(&acc[(size_t)a + (size_t)lane * XYg], wd * f);
    }
}

extern "C" void kernel_launch(void* const* d_in, const int* in_sizes, int n_in,
                              void* d_out, int out_size, void* d_ws, size_t ws_size,
                              hipStream_t stream) {
    const float* xf     = (const float*)d_in[0];
    const float* rots   = (const float*)d_in[1];
    const float* trans  = (const float*)d_in[2];
    const float* intr   = (const float*)d_in[3];
    const float* prots  = (const float*)d_in[4];
    const float* ptrans = (const float*)d_in[5];
    float* out = (float*)d_out;

    if (ws_size >= (size_t)WS_NEED) {
        char* wsb = (char*)d_ws;
        float* ws = (float*)wsb;
        int* claim = (int*)(wsb + CLAIM_OFF);
        unsigned char* bmapT = (unsigned char*)(wsb + BMAPT_OFF);
        hipMemsetAsync(claim, 0, CTL_BYTES, stream);   // claims + bmapT only
        lss_scatter_claim<<<dim3(NCOL), dim3(256), 0, stream>>>(
            xf, rots, trans, intr, prots, ptrans, ws, claim, bmapT);
        lss_transpose_c2<<<dim3(NTILE), dim3(256), 0, stream>>>(
            ws, claim, bmapT, out);
    } else {
        lss_zero<<<dim3(2048), dim3(256), 0, stream>>>(
            (float4*)out, (BB*NZg*XYg*CC)/4);
        lss_scatter_direct<<<dim3((NPIX + 3) / 4), dim3(256), 0, stream>>>(
            xf, rots, trans, intr, prots, ptrans, out);
    }
}

// Round 19
// 44.827 us; speedup vs baseline: 20.9261x; 20.9261x over previous
//
#include <hip/hip_runtime.h>
#include <math.h>

#define BB 4
#define NN 6
#define DD 41
#define CC 64
#define FHh 16
#define FWw 44
#define NXg 200
#define NYg 200
#define NZg 1
#define NSLOT 128
#define NOVF  (FHh*DD)                 // 656 worst-case points per column
#define XYg (NXg*NYg)                  // 40000
#define NVOX (BB*NZg*NXg*NYg)          // 160000
#define NCOL (BB*NN*FWw)               // 1056 columns
#define NPIX (BB*NN*FHh*FWw)           // 16896
#define NCH  (DD+CC)                   // 105
#define NTILE (NVOX/64)                // 2500

// ws layout: wsv[NVOX][CC] floats, then per-TILE byte map bmapT[NTILE]
#define WSV_BYTES  (NVOX*CC*4u)        // 40,960,000
#define BMAP_OFF   WSV_BYTES
#define ZERO_BYTES (WSV_BYTES + 2560u) // wsv + tile map (16B multiple)
#define WS_NEED    ZERO_BYTES

__device__ __forceinline__ void inv3x3d(const double m[9], double o[9]) {
    double a=m[0],b=m[1],c=m[2],d=m[3],e=m[4],f=m[5],g=m[6],h=m[7],i=m[8];
    double A = e*i - f*h;
    double Bv = -(d*i - f*g);
    double Cv = d*h - e*g;
    double det = a*A + b*Bv + c*Cv;
    double r = 1.0/det;
    o[0]=A*r;  o[1]=-(b*i-c*h)*r; o[2]=(b*f-c*e)*r;
    o[3]=Bv*r; o[4]=(a*i-c*g)*r;  o[5]=-(a*f-c*d)*r;
    o[6]=Cv*r; o[7]=-(a*h-b*g)*r; o[8]=(a*e-b*d)*r;
}

// fast zero-fill: grid-stride float4 (covers wsv + tile map)
__global__ __launch_bounds__(256)
void lss_zero(float4* __restrict__ p, int n4)
{
    const int stride = gridDim.x * 256;
    for (int i = blockIdx.x * 256 + threadIdx.x; i < n4; i += stride)
        p[i] = make_float4(0.f, 0.f, 0.f, 0.f);
}

// One block (256 thr, 4 waves) per (b,n,w) column; wave wv handles h=4wv..4wv+3.
// Logits are loaded straight from global (prefetched, no LDS round-trip);
// only the reused feature slice is staged. Dedup voxels in an LDS hash table,
// then ONE 64-lane contiguous atomic set per unique voxel into ws[vox][64c],
// flagging bmapT[vox>>6]=1 (plain byte store) for the gated transpose.
__global__ __launch_bounds__(256)
void lss_scatter_dedup(const float* __restrict__ xf,
                       const float* __restrict__ rots,
                       const float* __restrict__ trans,
                       const float* __restrict__ intr,
                       const float* __restrict__ prots,
                       const float* __restrict__ ptrans,
                       float* __restrict__ ws,
                       unsigned char* __restrict__ bmapT)
{
    __shared__ float s_feat[FHh * CC];       // feats  [h][c]
    __shared__ float s_coef[NSLOT * 17];     // per-slot per-h coefficient (pad 17)
    __shared__ int   s_keys[NSLOT];
    __shared__ short s_list[NSLOT];          // compacted occupied-slot list
    __shared__ int   s_nslot;
    __shared__ int2  s_ovf[NOVF];
    __shared__ float s_ovfw[NOVF];
    __shared__ int   s_ovfcnt;

    const int tid  = threadIdx.x;
    const int lane = tid & 63;
    const int wv   = tid >> 6;          // 0..3

    // XCD swizzle: 1056 = 8*132; each XCD gets a contiguous run of columns
    const int obid = blockIdx.x;
    const int bid  = (obid & 7) * (NCOL / 8) + (obid >> 3);
    const int w   = bid % FWw;
    const int rem = bid / FWw;
    const int n   = rem % NN;
    const int b   = rem / NN;
    const int cam = b*NN + n;
    const float* colbase = xf + (size_t)cam * NCH * FHh * FWw + w;

    // ---- prefetch this lane's 4 logits (independent, in flight early) ----
    float lgt[4];
    #pragma unroll
    for (int r = 0; r < 4; ++r) {
        const int h = (wv << 2) + r;
        lgt[r] = (lane < DD)
            ? colbase[(size_t)lane * (FHh*FWw) + h * FWw] : -INFINITY;
    }

    if (tid < NSLOT) s_keys[tid] = -1;
    for (int i = tid; i < NSLOT*17; i += 256) s_coef[i] = 0.0f;
    if (tid == 0) { s_nslot = 0; s_ovfcnt = 0; }

    // ---- stage only the reused features: 1024 scalars ----
    for (int t = tid; t < FHh*CC; t += 256) {
        int h = t >> 6, c = t & 63;
        s_feat[t] = colbase[(size_t)(DD + c) * (FHh*FWw) + h * FWw];
    }

    // ---- per-camera transform (double precision, redundant per thread) ----
    double K9[9], P9[9], R9[9];
    #pragma unroll
    for (int i = 0; i < 9; ++i) {
        K9[i] = (double)intr [cam*9 + i];
        P9[i] = (double)prots[cam*9 + i];
        R9[i] = (double)rots [cam*9 + i];
    }
    double Kinv[9], Pinv[9];
    inv3x3d(K9, Kinv);
    inv3x3d(P9, Pinv);
    double M[9];
    #pragma unroll
    for (int i = 0; i < 3; ++i)
        #pragma unroll
        for (int j = 0; j < 3; ++j)
            M[i*3+j] = R9[i*3+0]*Kinv[0*3+j] + R9[i*3+1]*Kinv[1*3+j] + R9[i*3+2]*Kinv[2*3+j];
    const double tx  = (double)trans [cam*3+0], ty  = (double)trans [cam*3+1], tz  = (double)trans [cam*3+2];
    const double ptx = (double)ptrans[cam*3+0], pty = (double)ptrans[cam*3+1], ptz = (double)ptrans[cam*3+2];

    __syncthreads();   // s_keys/s_coef init + s_feat visible

    // ---- softmax + geometry + hash insert; wave wv handles h = 4wv..4wv+3
    int      last_vox  = -1;     // per-lane (vox -> slot) cache across h
    unsigned last_slot = 0;
    for (int r = 0; r < 4; ++r) {
        const int h = (wv << 2) + r;
        float logit = lgt[r];
        float mx = logit;
        #pragma unroll
        for (int off = 32; off; off >>= 1) mx = fmaxf(mx, __shfl_xor(mx, off));
        float ex = (lane < DD) ? expf(logit - mx) : 0.0f;
        float sm = ex;
        #pragma unroll
        for (int off = 32; off; off >>= 1) sm += __shfl_xor(sm, off);
        const float wgt = ex / sm;

        int vox = -1;
        if (lane < DD) {
            double dz = 4.0 + (double)lane;
            double xs = (double)w * (703.0/43.0);
            double ys = (double)h * 17.0;
            double px = xs - ptx, py = ys - pty, pz = dz - ptz;
            double qx = Pinv[0]*px + Pinv[1]*py + Pinv[2]*pz;
            double qy = Pinv[3]*px + Pinv[4]*py + Pinv[5]*pz;
            double qz = Pinv[6]*px + Pinv[7]*py + Pinv[8]*pz;
            qx *= qz; qy *= qz;
            double gx = M[0]*qx + M[1]*qy + M[2]*qz + tx;
            double gy = M[3]*qx + M[4]*qy + M[5]*qz + ty;
            double gz = M[6]*qx + M[7]*qy + M[8]*qz + tz;
            double fx = floor((gx + 50.0) / 0.5);
            double fy = floor((gy + 50.0) / 0.5);
            double fz = floor((gz + 10.0) / 20.0);
            if (fx >= 0.0 && fx < (double)NXg &&
                fy >= 0.0 && fy < (double)NYg &&
                fz >= 0.0 && fz < (double)NZg) {
                int ix = (int)fx, iy = (int)fy, iz = (int)fz;
                vox = ((b*NZg + iz)*NXg + ix)*NYg + iy;   // < 160000
            }
        }

        if (vox >= 0) {
            if (vox == last_vox) {
                atomicAdd(&s_coef[last_slot*17 + h], wgt);
            } else {
                unsigned slot = (((unsigned)vox * 2654435761u) >> 18) & (NSLOT-1);
                bool done = false;
                for (int probe = 0; probe < NSLOT; ++probe) {
                    int prev = atomicCAS(&s_keys[slot], -1, vox);
                    if (prev == -1) {
                        int k = atomicAdd(&s_nslot, 1);
                        s_list[k] = (short)slot;
                    }
                    if (prev == -1 || prev == vox) {
                        atomicAdd(&s_coef[slot*17 + h], wgt);
                        last_vox = vox; last_slot = slot;
                        done = true;
                        break;
                    }
                    slot = (slot + 1) & (NSLOT-1);
                }
                if (!done) {   // table full: spill (generic-correctness fallback)
                    int k = atomicAdd(&s_ovfcnt, 1);
                    s_ovf[k]  = make_int2(vox, h);
                    s_ovfw[k] = wgt;
                    last_vox = -1;
                }
            }
        }
    }

    __syncthreads();

    // ---- hoist this lane's 16 feature values into registers ----
    float freg[FHh];
    #pragma unroll
    for (int h = 0; h < FHh; ++h) freg[h] = s_feat[(h << 6) + lane];

    // ---- emit: one 64-lane contiguous atomic set per unique voxel ----
    const int nocc = s_nslot;
    for (int e = wv; e < nocc; e += 4) {
        int slot = s_list[e];
        int vox  = s_keys[slot];
        float acc = 0.0f;
        #pragma unroll
        for (int h = 0; h < FHh; ++h)
            acc += s_coef[slot*17 + h] * freg[h];
        atomicAdd(&ws[(size_t)vox * CC + lane], acc);
        if (lane == 0) bmapT[vox >> 6] = 1;   // tile-level flag (idempotent)
    }
    // ---- overflow entries (rare, generic fallback) ----
    const int novf = s_ovfcnt;
    for (int e = wv; e < novf; e += 4) {
        int vox = s_ovf[e].x, h = s_ovf[e].y;
        atomicAdd(&ws[(size_t)vox * CC + lane], s_ovfw[e] * freg[h]);
        if (lane == 0) bmapT[vox >> 6] = 1;
    }
}

// ws [bz][40000 xy][64 c] -> out [bz][64 c][40000 xy]; tile-byte-gated reads.
__global__ __launch_bounds__(256)
void lss_transpose_g(const float* __restrict__ ws,
                     const unsigned char* __restrict__ bmapT,
                     float* __restrict__ out)
{
    __shared__ float tile[CC][65];          // [c][xy], pad 65
    const int blk  = blockIdx.x;            // 2500 blocks; tile id == blk
    const int bz   = blk / 625;
    const int xy0  = (blk % 625) * 64;
    const int t    = threadIdx.x;
    const int lane = t & 63;
    const int wv   = t >> 6;                // 0..3

    float* dst = out + (size_t)bz * CC * XYg + xy0;
    if (bmapT[blk] == 0) {                  // one broadcast byte decides tile
        const float4 z = make_float4(0.f, 0.f, 0.f, 0.f);
        #pragma unroll
        for (int rep = 0; rep < 4; ++rep) {
            int c = (wv << 4) + (rep << 2) + (lane >> 4);
            int q = lane & 15;
            ((float4*)(dst + (size_t)c * XYg))[q] = z;
        }
        return;
    }

    const int vb = bz * XYg + xy0;          // 64-aligned voxel base
    const float4* src = (const float4*)(ws + (size_t)vb * CC);
    #pragma unroll
    for (int rep = 0; rep < 4; ++rep) {
        int idx = (wv << 8) + (rep << 6) + lane;   // 64 consecutive float4/wave
        int xyl = idx >> 4;                        // 0..63
        int c4  = idx & 15;                        // float4 group within c
        float4 v = src[idx];
        tile[(c4<<2)+0][xyl] = v.x;
        tile[(c4<<2)+1][xyl] = v.y;
        tile[(c4<<2)+2][xyl] = v.z;
        tile[(c4<<2)+3][xyl] = v.w;
    }
    __syncthreads();
    #pragma unroll
    for (int rep = 0; rep < 4; ++rep) {
        int c   = (wv << 4) + (rep << 2) + (lane >> 4);  // 0..63
        int xy4 = lane & 15;                             // float4 within row
        float4 v = make_float4(tile[c][(xy4<<2)+0], tile[c][(xy4<<2)+1],
                               tile[c][(xy4<<2)+2], tile[c][(xy4<<2)+3]);
        ((float4*)(dst + (size_t)c * XYg))[xy4] = v;
    }
}

// ---------------- fallback (tiny ws): zero out + direct atomics -------------
__global__ __launch_bounds__(256)
void lss_scatter_direct(const float* __restrict__ xf,
                        const float* __restrict__ rots,
                        const float* __restrict__ trans,
                        const float* __restrict__ intr,
                        const float* __restrict__ prots,
                        const float* __restrict__ ptrans,
                        float* __restrict__ acc)
{
    const int wid  = blockIdx.x * 4 + (threadIdx.x >> 6);
    const int lane = threadIdx.x & 63;
    if (wid >= NPIX) return;
    int w  = wid % FWw;
    int t1 = wid / FWw;
    int h  = t1 % FHh; t1 /= FHh;
    int n  = t1 % NN;
    int b  = t1 / NN;
    const int cam = b*NN + n;

    double K9[9], P9[9], R9[9];
    #pragma unroll
    for (int i = 0; i < 9; ++i) {
        K9[i] = (double)intr [cam*9 + i];
        P9[i] = (double)prots[cam*9 + i];
        R9[i] = (double)rots [cam*9 + i];
    }
    double Kinv[9], Pinv[9];
    inv3x3d(K9, Kinv);
    inv3x3d(P9, Pinv);
    double M[9];
    #pragma unroll
    for (int i = 0; i < 3; ++i)
        #pragma unroll
        for (int j = 0; j < 3; ++j)
            M[i*3+j] = R9[i*3+0]*Kinv[0*3+j] + R9[i*3+1]*Kinv[1*3+j] + R9[i*3+2]*Kinv[2*3+j];
    const double tx  = (double)trans [cam*3+0], ty  = (double)trans [cam*3+1], tz  = (double)trans [cam*3+2];
    const double ptx = (double)ptrans[cam*3+0], pty = (double)ptrans[cam*3+1], ptz = (double)ptrans[cam*3+2];

    const size_t pixoff = (size_t)cam * NCH * FHh * FWw + (size_t)h * FWw + w;
    float logit = (lane < DD) ? xf[pixoff + (size_t)lane * (FHh*FWw)] : -INFINITY;
    float mx = logit;
    #pragma unroll
    for (int off = 32; off; off >>= 1) mx = fmaxf(mx, __shfl_xor(mx, off));
    float ex = (lane < DD) ? expf(logit - mx) : 0.0f;
    float sm = ex;
    #pragma unroll
    for (int off = 32; off; off >>= 1) sm += __shfl_xor(sm, off);
    const float wgt = ex / sm;

    int baddr = -1;
    if (lane < DD) {
        double dz = 4.0 + (double)lane;
        double xs = (double)w * (703.0/43.0);
        double ys = (double)h * 17.0;
        double px = xs - ptx, py = ys - pty, pz = dz - ptz;
        double qx = Pinv[0]*px + Pinv[1]*py + Pinv[2]*pz;
        double qy = Pinv[3]*px + Pinv[4]*py + Pinv[5]*pz;
        double qz = Pinv[6]*px + Pinv[7]*py + Pinv[8]*pz;
        qx *= qz; qy *= qz;
        double gx = M[0]*qx + M[1]*qy + M[2]*qz + tx;
        double gy = M[3]*qx + M[4]*qy + M[5]*qz + ty;
        double gz = M[6]*qx + M[7]*qy + M[8]*qz + tz;
        double fx = floor((gx + 50.0) / 0.5);
        double fy = floor((gy + 50.0) / 0.5);
        double fz = floor((gz + 10.0) / 20.0);
        if (fx >= 0.0 && fx < (double)NXg &&
            fy >= 0.0 && fy < (double)NYg &&
            fz >= 0.0 && fz < (double)NZg) {
            int ix = (int)fx, iy = (int)fy, iz = (int)fz;
            int bz = b*NZg + iz;
            baddr = bz * (CC*XYg) + ix*NYg + iy;
        }
    }

    const float f = xf[pixoff + (size_t)(DD + lane) * (FHh*FWw)];
    for (int d = 0; d < DD; ++d) {
        int   a  = __shfl(baddr, d);
        float wd = __shfl(wgt,   d);
        if (a >= 0) atomicAdd(&acc[(size_t)a + (size_t)lane * XYg], wd * f);
    }
}

extern "C" void kernel_launch(void* const* d_in, const int* in_sizes, int n_in,
                              void* d_out, int out_size, void* d_ws, size_t ws_size,
                              hipStream_t stream) {
    const float* xf     = (const float*)d_in[0];
    const float* rots   = (const float*)d_in[1];
    const float* trans  = (const float*)d_in[2];
    const float* intr   = (const float*)d_in[3];
    const float* prots  = (const float*)d_in[4];
    const float* ptrans = (const float*)d_in[5];
    float* out = (float*)d_out;

    if (ws_size >= (size_t)WS_NEED) {
        char* wsb = (char*)d_ws;
        float* ws = (float*)wsb;
        unsigned char* bmapT = (unsigned char*)(wsb + BMAP_OFF);
        lss_zero<<<dim3(2048), dim3(256), 0, stream>>>(
            (float4*)wsb, ZERO_BYTES/16);
        lss_scatter_dedup<<<dim3(NCOL), dim3(256), 0, stream>>>(
            xf, rots, trans, intr, prots, ptrans, ws, bmapT);
        lss_transpose_g<<<dim3(NTILE), dim3(256), 0, stream>>>(
            ws, bmapT, out);
    } else {
        lss_zero<<<dim3(2048), dim3(256), 0, stream>>>(
            (float4*)out, (BB*NZg*XYg*CC)/4);
        lss_scatter_direct<<<dim3((NPIX + 3) / 4), dim3(256), 0, stream>>>(
            xf, rots, trans, intr, prots, ptrans, out);
    }
}